// Round 8
// baseline (36.480 us; speedup 1.0000x reference)
//
#include <hip/hip_runtime.h>

typedef float f32x2 __attribute__((ext_vector_type(2)));
typedef float f32x4 __attribute__((ext_vector_type(4)));

#define BB 4
#define CC 3
#define HH 1024
#define WW 1024
#define NCHUNK (WW / 4)   // 256 float4 chunks per row

static __device__ __forceinline__ f32x2 splat2(float s) {
    f32x2 v; v.x = s; v.y = s; return v;
}

__global__ __launch_bounds__(128, 3) void dpmerge_kernel(
    const float* __restrict__ image,   // (B,C,H,W)
    const float* __restrict__ depth,   // (B,H,W)
    float* __restrict__ out)           // left (B,C,H,W) then right (B,C,H,W)
{
    const int row = blockIdx.x;        // 0 .. B*H-1
    const int b   = row >> 10;
    const int h   = row & (HH - 1);
    const int tid = threadIdx.x;       // 0..127
    const int x0  = 8 * tid;           // this thread's 8 output pixels
    const float xb = (float)x0;

    const size_t chStride = (size_t)HH * WW;
    const size_t imgBase  = ((size_t)b * CC) * chStride + (size_t)h * WW;
    const size_t NV       = (size_t)BB * CC * chStride;   // right-view offset

    const f32x4* Drow = reinterpret_cast<const f32x4*>(depth + (size_t)row * WW);
    const f32x4* I0   = reinterpret_cast<const f32x4*>(image + imgBase);
    const f32x4* I1   = reinterpret_cast<const f32x4*>(image + imgBase + chStride);
    const f32x4* I2   = reinterpret_cast<const f32x4*>(image + imgBase + 2 * chStride);

    // ---- depth union window: s in [x0-8, x0+15] -> chunks 2tid-2 .. 2tid+3 ----
    float dw[24];
#pragma unroll
    for (int i = 0; i < 6; ++i) {
        int c = 2 * tid - 2 + i;
        c = c < 0 ? 0 : (c > NCHUNK - 1 ? NCHUNK - 1 : c);
        const f32x4 v = Drow[c];
        dw[4*i+0] = v.x; dw[4*i+1] = v.y; dw[4*i+2] = v.z; dw[4*i+3] = v.w;
    }
    if (tid == 0) {            // s = x0-8+u < 0 for u<8 (left view only)
#pragma unroll
        for (int u = 0; u < 8; ++u) dw[u] = 1e30f;
    }
    if (tid == 127) {          // s = x0-8+u >= W for u>=16 (right view only)
#pragma unroll
        for (int u = 16; u < 24; ++u) dw[u] = 1e30f;
    }

    // pos arrays, bit-identical to reference: fl(float(s) +- d)
    float posL[16];            // u: s = x0-8+u, u in [0,16)
    float posR[16];            // v: s = x0+v,   v in [0,16)
#pragma unroll
    for (int u = 0; u < 16; ++u) posL[u] = (xb + (float)(u - 8)) + dw[u];
#pragma unroll
    for (int v = 0; v < 16; ++v) posR[v] = (xb + (float)v) - dw[v + 8];

    // One view: im window chunks CBASE..CBASE+3 (16 source pixels aligned with
    // POS idx), 4 packed pixel-pairs, nontemporal store of 8 px * 3 channels.
#define VIEW(POS, CBASE, OBASE)                                                 \
    {                                                                           \
        float im0[16], im1[16], im2[16];                                        \
        _Pragma("unroll")                                                       \
        for (int i = 0; i < 4; ++i) {                                           \
            int c = (CBASE) + i;                                                \
            c = c < 0 ? 0 : (c > NCHUNK - 1 ? NCHUNK - 1 : c);                  \
            const f32x4 v0 = I0[c];                                             \
            const f32x4 v1 = I1[c];                                             \
            const f32x4 v2 = I2[c];                                             \
            im0[4*i+0] = v0.x; im0[4*i+1] = v0.y; im0[4*i+2] = v0.z; im0[4*i+3] = v0.w; \
            im1[4*i+0] = v1.x; im1[4*i+1] = v1.y; im1[4*i+2] = v1.z; im1[4*i+3] = v1.w; \
            im2[4*i+0] = v2.x; im2[4*i+1] = v2.y; im2[4*i+2] = v2.z; im2[4*i+3] = v2.w; \
        }                                                                       \
        float r0[8], r1[8], r2[8];                                              \
        _Pragma("unroll")                                                       \
        for (int jp = 0; jp < 4; ++jp) {                                        \
            const int j = 2 * jp;                                               \
            f32x2 xf2; xf2.x = xb + (float)j; xf2.y = xb + (float)(j + 1);      \
            f32x2 cn = splat2(0.f), A0 = splat2(0.f);                           \
            f32x2 A1 = splat2(0.f), A2 = splat2(0.f);                           \
            _Pragma("unroll")                                                   \
            for (int i = 0; i < 10; ++i) {                                      \
                const int   u = j + i;                                          \
                const f32x2 t = splat2((POS)[u]) - xf2;                         \
                const f32x2 w = __builtin_elementwise_max(                      \
                    splat2(1.0f) - __builtin_elementwise_abs(t), splat2(0.f));  \
                cn += w;                                                        \
                A0 += splat2(im0[u]) * w;                                       \
                A1 += splat2(im1[u]) * w;                                       \
                A2 += splat2(im2[u]) * w;                                       \
            }                                                                   \
            const float ix = __builtin_amdgcn_rcpf(fmaxf(cn.x, 1e-30f));        \
            const float iy = __builtin_amdgcn_rcpf(fmaxf(cn.y, 1e-30f));        \
            r0[j] = A0.x * ix; r0[j+1] = A0.y * iy;                             \
            r1[j] = A1.x * ix; r1[j+1] = A1.y * iy;                             \
            r2[j] = A2.x * ix; r2[j+1] = A2.y * iy;                             \
        }                                                                       \
        f32x4 q;                                                                \
        q.x = r0[0]; q.y = r0[1]; q.z = r0[2]; q.w = r0[3];                     \
        __builtin_nontemporal_store(q, reinterpret_cast<f32x4*>(out + (OBASE) + x0));     \
        q.x = r0[4]; q.y = r0[5]; q.z = r0[6]; q.w = r0[7];                     \
        __builtin_nontemporal_store(q, reinterpret_cast<f32x4*>(out + (OBASE) + x0 + 4)); \
        q.x = r1[0]; q.y = r1[1]; q.z = r1[2]; q.w = r1[3];                     \
        __builtin_nontemporal_store(q, reinterpret_cast<f32x4*>(out + (OBASE) + chStride + x0));     \
        q.x = r1[4]; q.y = r1[5]; q.z = r1[6]; q.w = r1[7];                     \
        __builtin_nontemporal_store(q, reinterpret_cast<f32x4*>(out + (OBASE) + chStride + x0 + 4)); \
        q.x = r2[0]; q.y = r2[1]; q.z = r2[2]; q.w = r2[3];                     \
        __builtin_nontemporal_store(q, reinterpret_cast<f32x4*>(out + (OBASE) + 2 * chStride + x0));     \
        q.x = r2[4]; q.y = r2[5]; q.z = r2[6]; q.w = r2[7];                     \
        __builtin_nontemporal_store(q, reinterpret_cast<f32x4*>(out + (OBASE) + 2 * chStride + x0 + 4)); \
    }

    // LEFT view: sources s in [x0-8, x0+7] -> chunks 2tid-2..2tid+1
    VIEW(posL, 2 * tid - 2, imgBase);
    // RIGHT view: sources s in [x0, x0+15] -> chunks 2tid..2tid+3
    VIEW(posR, 2 * tid, NV + imgBase);
#undef VIEW
}

extern "C" void kernel_launch(void* const* d_in, const int* in_sizes, int n_in,
                              void* d_out, int out_size, void* d_ws, size_t ws_size,
                              hipStream_t stream) {
    const float* image = (const float*)d_in[0];
    const float* depth = (const float*)d_in[1];
    float* out = (float*)d_out;
    (void)in_sizes; (void)n_in; (void)out_size; (void)d_ws; (void)ws_size;

    dim3 grid(BB * HH);   // 4096 rows
    dim3 block(128);      // 8 px per thread
    hipLaunchKernelGGL(dpmerge_kernel, grid, block, 0, stream, image, depth, out);
}

// Round 9
// 32.329 us; speedup vs baseline: 1.1284x; 1.1284x over previous
//
#include <hip/hip_runtime.h>

typedef float f32x4 __attribute__((ext_vector_type(4)));

#define BB 4
#define CC 3
#define HH 1024
#define WW 1024
#define NCHUNK (WW / 4)   // 256 float4 chunks per row

__global__ __launch_bounds__(512) void dpmerge_kernel(
    const float* __restrict__ image,   // (B,C,H,W)
    const float* __restrict__ depth,   // (B,H,W)
    float* __restrict__ out)           // left (B,C,H,W) then right (B,C,H,W)
{
    const int row  = blockIdx.x;       // 0 .. B*H-1
    const int b    = row >> 10;
    const int h    = row & (HH - 1);
    const int tid  = threadIdx.x;      // 0..511
    const int vtid = tid & 255;        // pixel-group id within the view
    const bool isL = tid < 256;        // wave-uniform view split
    const int x0   = 4 * vtid;         // this thread's 4 output pixels
    const float xb = (float)x0;

    const size_t chStride = (size_t)HH * WW;
    const size_t imgBase  = ((size_t)b * CC) * chStride + (size_t)h * WW;
    const size_t NV       = (size_t)BB * CC * chStride;   // right-view offset

    const f32x4* Drow = reinterpret_cast<const f32x4*>(depth + (size_t)row * WW);
    const f32x4* I0   = reinterpret_cast<const f32x4*>(image + imgBase);
    const f32x4* I1   = reinterpret_cast<const f32x4*>(image + imgBase + chStride);
    const f32x4* I2   = reinterpret_cast<const f32x4*>(image + imgBase + 2 * chStride);

    // Source window (12 wide):
    //   left view : s in [x0-8, x0+3]  -> chunks vtid-2 .. vtid
    //   right view: s in [x0,   x0+11] -> chunks vtid   .. vtid+2
    const int cbase = isL ? (vtid - 2) : vtid;

    float dw[12], im0[12], im1[12], im2[12];
#pragma unroll
    for (int i = 0; i < 3; ++i) {
        int c = cbase + i;
        c = c < 0 ? 0 : (c > NCHUNK - 1 ? NCHUNK - 1 : c);
        const f32x4 dv = Drow[c];
        const f32x4 v0 = I0[c];
        const f32x4 v1 = I1[c];
        const f32x4 v2 = I2[c];
        dw [4*i+0] = dv.x; dw [4*i+1] = dv.y; dw [4*i+2] = dv.z; dw [4*i+3] = dv.w;
        im0[4*i+0] = v0.x; im0[4*i+1] = v0.y; im0[4*i+2] = v0.z; im0[4*i+3] = v0.w;
        im1[4*i+0] = v1.x; im1[4*i+1] = v1.y; im1[4*i+2] = v1.z; im1[4*i+3] = v1.w;
        im2[4*i+0] = v2.x; im2[4*i+1] = v2.y; im2[4*i+2] = v2.z; im2[4*i+3] = v2.w;
    }

    // Boundary poison (depth -> 1e30 makes the hat weight exactly 0).
    float pos[12];
    if (isL) {
        if (x0 < 8) {                        // vtid 0,1 only: s = x0-8+u < 0
#pragma unroll
            for (int u = 0; u < 8; ++u)
                if (x0 - 8 + u < 0) dw[u] = 1e30f;
        }
#pragma unroll
        for (int u = 0; u < 12; ++u)         // s = x0-8+u, pos = fl(s) + d
            pos[u] = (xb + (float)(u - 8)) + dw[u];
    } else {
        if (x0 + 11 >= WW) {                 // vtid 254,255: s = x0+u >= W
#pragma unroll
            for (int u = 4; u < 12; ++u)
                if (x0 + u >= WW) dw[u] = 1e30f;
        }
#pragma unroll
        for (int u = 0; u < 12; ++u)         // s = x0+u, pos = fl(s) - d
            pos[u] = (xb + (float)u) - dw[u];
    }

    // Pixel x0+j gathers window idx u = j..j+8 in both views.
    f32x4 oc0, oc1, oc2;
#pragma unroll
    for (int j = 0; j < 4; ++j) {
        const float xf = xb + (float)j;
        float cw = 0.f, a0 = 0.f, a1 = 0.f, a2 = 0.f;
#pragma unroll
        for (int i = 0; i < 9; ++i) {
            const int   u  = j + i;
            const float t  = pos[u] - xf;
            const float wt = fmaxf(1.0f - fabsf(t), 0.0f);
            cw += wt;
            a0 = fmaf(im0[u], wt, a0);
            a1 = fmaf(im1[u], wt, a1);
            a2 = fmaf(im2[u], wt, a2);
        }
        const float inv = __builtin_amdgcn_rcpf(fmaxf(cw, 1e-30f));
        oc0[j] = a0 * inv;
        oc1[j] = a1 * inv;
        oc2[j] = a2 * inv;
    }

    const size_t obase = isL ? imgBase : (NV + imgBase);
    __builtin_nontemporal_store(oc0, reinterpret_cast<f32x4*>(out + obase + x0));
    __builtin_nontemporal_store(oc1, reinterpret_cast<f32x4*>(out + obase + chStride + x0));
    __builtin_nontemporal_store(oc2, reinterpret_cast<f32x4*>(out + obase + 2 * chStride + x0));
}

extern "C" void kernel_launch(void* const* d_in, const int* in_sizes, int n_in,
                              void* d_out, int out_size, void* d_ws, size_t ws_size,
                              hipStream_t stream) {
    const float* image = (const float*)d_in[0];
    const float* depth = (const float*)d_in[1];
    float* out = (float*)d_out;
    (void)in_sizes; (void)n_in; (void)out_size; (void)d_ws; (void)ws_size;

    dim3 grid(BB * HH);   // 4096 rows, one block per row, both views
    dim3 block(512);
    hipLaunchKernelGGL(dpmerge_kernel, grid, block, 0, stream, image, depth, out);
}